// Round 19
// baseline (138.586 us; speedup 1.0000x reference)
//
#include <hip/hip_runtime.h>
#include <hip/hip_bf16.h>

typedef unsigned long long u64;
typedef unsigned int u32;

#define LOG2E 1.44269504088896340736f
#define LN2   0.69314718055994530942f
#define CAP   768

// ---------- fast math ----------
__device__ __forceinline__ float fexp2(float x) { return __builtin_amdgcn_exp2f(x); }
__device__ __forceinline__ float flog2(float x) { return __builtin_amdgcn_logf(x); }
__device__ __forceinline__ float frcp(float x)  { return __builtin_amdgcn_rcpf(x); }
__device__ __forceinline__ float keyval(u64 k) { return __uint_as_float((u32)(k >> 32)); }

__device__ __forceinline__ float iou_xyxy(float ax1, float ay1, float ax2, float ay2,
                                          float bx1, float by1, float bx2, float by2) {
    float ltx = fmaxf(ax1, bx1), lty = fmaxf(ay1, by1);
    float rbx = fminf(ax2, bx2), rby = fminf(ay2, by2);
    float w = fmaxf(rbx - ltx, 0.0f), h = fmaxf(rby - lty, 0.0f);
    float inter = w * h;
    float areaA = (ax2 - ax1) * (ay2 - ay1);
    float areaB = (bx2 - bx1) * (by2 - by1);
    return inter / (areaA + areaB - inter);
}

// ---------- chunk load (guarded; regs untouched when inactive) ----------
__device__ __forceinline__ void load_chunk(
        int chunk, int NBLK, int P, int n, int r, int sub,
        const float* __restrict__ conf, const float* __restrict__ priors,
        const float* __restrict__ loc,
        float4& L0, float4& L1, float4& L2, float4& L3, float4& L4,
        float4& prv, float4& lcv) {
    int p = chunk * 64 + r;
    if (chunk < NBLK && p < P) {
        const float* rowp = conf + ((size_t)n * P + p) * 80 + sub * 4;
        L0 = *(const float4*)(rowp);
        L1 = *(const float4*)(rowp + 16);
        L2 = *(const float4*)(rowp + 32);
        L3 = *(const float4*)(rowp + 48);
        L4 = *(const float4*)(rowp + 64);
        prv = *(const float4*)(priors + (size_t)p * 4);
        lcv = *(const float4*)(loc + ((size_t)n * P + p) * 4);
    }
}

// ---------- chunk compute (reg path + gfocal + pred + per-chunk reduce) ----------
__device__ __forceinline__ void compute_chunk(
        int chunk, int NBLK, int P, int n, int r, int sub, int tid,
        float4 L0, float4 L1, float4 L2, float4 L3, float4 L4,
        float4 prv, float4 lcv,
        const float* strt, const u32* smask, u32 mybits,
        float (*sglab)[17], float* wsum,
        u64* __restrict__ basekeyR, u64* __restrict__ basekeyP,
        double* __restrict__ partC) {
    int p = chunk * 64 + r;
    bool act = (chunk < NBLK) && (p < P);

    // ---- reg path
    {
        float vv[4] = {0, 0, 0, 0};
        float vmax = 0.0f;
        if (act) {
            float cx = prv.x + lcv.x * 0.1f * prv.z;
            float cy = prv.y + lcv.y * 0.1f * prv.w;
            float w  = prv.z * fexp2(lcv.z * 0.2f * LOG2E);
            float h  = prv.w * fexp2(lcv.w * 0.2f * LOG2E);
            float bx1 = cx - w * 0.5f, by1 = cy - h * 0.5f;
            float bx2 = cx + w * 0.5f, by2 = cy + h * 0.5f;
            #pragma unroll
            for (int jj = 0; jj < 4; jj++) {
                int o = sub * 4 + jj;
                float v = iou_xyxy(strt[o * 4], strt[o * 4 + 1], strt[o * 4 + 2],
                                   strt[o * 4 + 3], bx1, by1, bx2, by2);
                vv[jj] = v;
                vmax = fmaxf(vmax, v);
            }
        }
        vmax = fmaxf(vmax, __shfl_xor(vmax, 1, 64));
        vmax = fmaxf(vmax, __shfl_xor(vmax, 2, 64));
        u32 bits = 0;
        #pragma unroll
        for (int jj = 0; jj < 4; jj++) {
            if (act && vv[jj] == vmax) bits |= 1u << (sub * 4 + jj);
        }
        bits |= __shfl_xor(bits, 1, 64);
        bits |= __shfl_xor(bits, 2, 64);
        if (act && sub == 0) {
            basekeyR[(size_t)n * P + p] = ((u64)__float_as_uint(vmax) << 32) | bits;
        }
    }

    // ---- gfocal stream, t = 0 everywhere (corrections in k_tail)
    float lsum = 0.0f;
    if (act) {
        float lv[20] = {L0.x, L0.y, L0.z, L0.w, L1.x, L1.y, L1.z, L1.w,
                        L2.x, L2.y, L2.z, L2.w, L3.x, L3.y, L3.z, L3.w,
                        L4.x, L4.y, L4.z, L4.w};
        #pragma unroll
        for (int k = 0; k < 5; k++) {
            #pragma unroll
            for (int j = 0; j < 4; j++) {
                float lg = lv[k * 4 + j];
                float e  = fexp2(-fabsf(lg) * LOG2E);
                float ln1pe = flog2(1.0f + e) * LN2;
                float rc = frcp(1.0f + e);
                float sg = (lg >= 0.0f) ? rc : e * rc;
                lsum += sg * sg * (fmaxf(lg, 0.0f) + ln1pe);
                if (mybits & (1u << (k * 4 + j))) {
                    u32 m16 = smask[k * 16 + sub * 4 + j];
                    while (m16) {
                        int o = __ffs(m16) - 1;
                        sglab[r][o] = sg;
                        m16 &= m16 - 1;
                    }
                }
            }
        }
    }
    __syncthreads();

    // ---- pred path
    {
        float pv[4] = {0, 0, 0, 0};
        float pmax = 0.0f;
        if (act) {
            float px1 = prv.x - prv.z * 0.5f, py1 = prv.y - prv.w * 0.5f;
            float px2 = prv.x + prv.z * 0.5f, py2 = prv.y + prv.w * 0.5f;
            #pragma unroll
            for (int jj = 0; jj < 4; jj++) {
                int o = sub * 4 + jj;
                float ov = iou_xyxy(strt[o * 4], strt[o * 4 + 1], strt[o * 4 + 2],
                                    strt[o * 4 + 3], px1, py1, px2, py2);
                float pd = 0.0f;
                if (ov > 0.0f) {
                    float pc = sglab[r][o];
                    pd = fexp2((2.0f - pc) * 0.5f * flog2(ov));
                }
                pv[jj] = pd;
                pmax = fmaxf(pmax, pd);
            }
        }
        pmax = fmaxf(pmax, __shfl_xor(pmax, 1, 64));
        pmax = fmaxf(pmax, __shfl_xor(pmax, 2, 64));
        u32 bits = 0;
        #pragma unroll
        for (int jj = 0; jj < 4; jj++) {
            if (act && pv[jj] == pmax) bits |= 1u << (sub * 4 + jj);
        }
        bits |= __shfl_xor(bits, 1, 64);
        bits |= __shfl_xor(bits, 2, 64);
        if (act && sub == 0) {
            basekeyP[(size_t)n * P + p] = ((u64)__float_as_uint(pmax) << 32) | bits;
        }
    }

    // ---- per-chunk block reduce -> per-chunk slot
    #pragma unroll
    for (int s = 32; s > 0; s >>= 1) lsum += __shfl_down(lsum, s, 64);
    if ((tid & 63) == 0) wsum[tid >> 6] = lsum;
    __syncthreads();
    if (tid == 0 && chunk < NBLK) {
        partC[(size_t)n * NBLK + chunk] =
            (double)wsum[0] + (double)wsum[1] + (double)wsum[2] + (double)wsum[3];
    }
}

// ---------- K1: fused main pass, 4 chunks/block, double-buffered prefetch ----------
__global__ __launch_bounds__(256) void k_main(
        const float* __restrict__ loc, const float* __restrict__ conf,
        const float* __restrict__ priors, const float* __restrict__ truths,
        const int* __restrict__ labels,
        u64* __restrict__ basekeyR, u64* __restrict__ basekeyP,
        double* __restrict__ partC, u32* __restrict__ pcnt, u32* __restrict__ pcnt2,
        int P, int NBLK) {
    int n = blockIdx.y, tid = threadIdx.x;
    int r = tid >> 2, sub = tid & 3;
    int c0 = blockIdx.x * 4;

    if (blockIdx.x == 0 && tid == 0) { pcnt[n] = 0u; pcnt2[n] = 0u; }

    // issue first two chunks' loads before LDS setup (in flight across barriers)
    float4 A0, A1, A2, A3, A4, Ap, Al;
    float4 B0, B1, B2, B3, B4, Bp, Bl;
    A0 = A1 = A2 = A3 = A4 = Ap = Al = make_float4(0.f, 0.f, 0.f, 0.f);
    B0 = B1 = B2 = B3 = B4 = Bp = Bl = make_float4(0.f, 0.f, 0.f, 0.f);
    load_chunk(c0,     NBLK, P, n, r, sub, conf, priors, loc, A0, A1, A2, A3, A4, Ap, Al);
    load_chunk(c0 + 1, NBLK, P, n, r, sub, conf, priors, loc, B0, B1, B2, B3, B4, Bp, Bl);

    __shared__ float strt[64];
    __shared__ int   lab[16];
    __shared__ u32   smask[80];
    __shared__ float sglab[64][17];
    __shared__ float wsum[4];
    if (tid < 64) strt[tid] = truths[n * 64 + tid];
    if (tid < 80) smask[tid] = 0u;
    __syncthreads();
    if (tid < 16) {
        int lb = labels[n * 16 + tid];
        lab[tid] = lb;
        atomicOr(&smask[lb], 1u << tid);
    }
    __syncthreads();

    u32 mybits = 0;
    #pragma unroll
    for (int k = 0; k < 5; k++) {
        #pragma unroll
        for (int j = 0; j < 4; j++) {
            if (smask[k * 16 + sub * 4 + j]) mybits |= 1u << (k * 4 + j);
        }
    }

    // pipelined: compute A | load A' | compute B | load B' | compute A' | compute B'
    compute_chunk(c0, NBLK, P, n, r, sub, tid, A0, A1, A2, A3, A4, Ap, Al,
                  strt, smask, mybits, sglab, wsum, basekeyR, basekeyP, partC);
    load_chunk(c0 + 2, NBLK, P, n, r, sub, conf, priors, loc, A0, A1, A2, A3, A4, Ap, Al);
    compute_chunk(c0 + 1, NBLK, P, n, r, sub, tid, B0, B1, B2, B3, B4, Bp, Bl,
                  strt, smask, mybits, sglab, wsum, basekeyR, basekeyP, partC);
    load_chunk(c0 + 3, NBLK, P, n, r, sub, conf, priors, loc, B0, B1, B2, B3, B4, Bp, Bl);
    compute_chunk(c0 + 2, NBLK, P, n, r, sub, tid, A0, A1, A2, A3, A4, Ap, Al,
                  strt, smask, mybits, sglab, wsum, basekeyR, basekeyP, partC);
    compute_chunk(c0 + 3, NBLK, P, n, r, sub, tid, B0, B1, B2, B3, B4, Bp, Bl,
                  strt, smask, mybits, sglab, wsum, basekeyR, basekeyP, partC);
}

// ---------- K2: per-(row,z) exact top-15 via histogram radix-select ----------
__global__ __launch_bounds__(256) void k_sel(
        const u64* __restrict__ basekeyR, const u64* __restrict__ basekeyP,
        u64* __restrict__ selk, int P, int ROWS) {
    int row = blockIdx.x, z = blockIdx.y, tid = threadIdx.x;
    int n = row >> 4, o = row & 15;
    const u64* base = (z ? basekeyP : basekeyR) + (size_t)n * P;

    __shared__ u32 hist[2048];
    __shared__ u32 tsum[256];
    __shared__ int sB;
    __shared__ u32 sSB;
    __shared__ u32 sT;
    __shared__ u64 cand[CAP];
    __shared__ u32 scnt;
    __shared__ u64 sel[15];

    if (tid == 0) scnt = 0u;
    if (tid < 15) sel[tid] = 0ULL;

    u64 pmask = 0, pval = 0;
    int shift = 53;
    int k = 0;
    int need = 15;
    bool done = false;

    for (int lvl = 0; lvl < 3 && !done; lvl++) {
        #pragma unroll
        for (int i = 0; i < 8; i++) hist[tid + i * 256] = 0u;
        __syncthreads();
        for (int i = tid * 2; i < P; i += 512) {
            ulonglong2 v = *(const ulonglong2*)(base + i);
            u64 b0 = v.x, b1 = v.y;
            if ((u32)(b0 >> 32) != 0u && ((b0 >> o) & 1) && (b0 & pmask) == pval)
                atomicAdd(&hist[(u32)(b0 >> shift) & 2047u], 1u);
            if ((u32)(b1 >> 32) != 0u && ((b1 >> o) & 1) && (b1 & pmask) == pval)
                atomicAdd(&hist[(u32)(b1 >> shift) & 2047u], 1u);
        }
        __syncthreads();
        u32 l_[8], ls[8];
        #pragma unroll
        for (int i = 0; i < 8; i++) l_[i] = hist[tid * 8 + i];
        ls[7] = l_[7];
        #pragma unroll
        for (int i = 6; i >= 0; i--) ls[i] = ls[i + 1] + l_[i];
        tsum[tid] = ls[0];
        __syncthreads();
        for (int d = 1; d < 256; d <<= 1) {
            u32 v = (tid + d < 256) ? tsum[tid + d] : 0u;
            __syncthreads();
            tsum[tid] += v;
            __syncthreads();
        }
        if (lvl == 0) {
            if (tid == 0) sT = tsum[0];
            __syncthreads();
            u32 T = sT;
            if (T == 0u) { k = 0; break; }
            k = (T < 15u) ? (int)T : 15;
            need = k;
        }
        u32 off = (tid < 255) ? tsum[tid + 1] : 0u;
        int myB = -1;
        #pragma unroll
        for (int i = 0; i < 8; i++) {
            u32 S = ls[i] + off;
            if ((int)S >= need) { int b = tid * 8 + i; if (b > myB) myB = b; }
        }
        if (tid == 0) sB = -1;
        __syncthreads();
        if (myB >= 0) atomicMax(&sB, myB);
        __syncthreads();
        int B = sB;
        if (B >= 0 && (B >> 3) == tid) sSB = ls[B & 7] + off;
        __syncthreads();
        u32 SB = sSB;
        bool last = (lvl == 2);
        bool fits = ((scnt + SB) <= (u32)CAP) || last;
        for (int i = tid * 2; i < P; i += 512) {
            ulonglong2 v = *(const ulonglong2*)(base + i);
            #pragma unroll
            for (int j = 0; j < 2; j++) {
                u64 b = (j == 0) ? v.x : v.y;
                int pp = i + j;
                if ((u32)(b >> 32) != 0u && ((b >> o) & 1) && (b & pmask) == pval) {
                    int bin = (int)((u32)(b >> shift) & 2047u);
                    bool take = fits ? (bin >= B) : (bin > B);
                    if (take) {
                        u32 idx = atomicAdd(&scnt, 1u);
                        if (idx < (u32)CAP)
                            cand[idx] = (b & 0xFFFFFFFF00000000ULL) | (u32)(~(u32)pp);
                    }
                }
            }
        }
        __syncthreads();
        if (fits) {
            done = true;
        } else {
            need = k - (int)scnt;
            pmask |= (u64)2047u << shift;
            pval |= ((u64)(u32)B) << shift;
            shift -= 11;
            __syncthreads();
        }
    }

    __syncthreads();
    if (k > 0) {
        u32 cnt = scnt; if (cnt > (u32)CAP) cnt = (u32)CAP;
        for (u32 i = tid; i < cnt; i += 256) {
            u64 key = cand[i];
            int rank = 0;
            for (u32 c = 0; c < cnt; c++) rank += (cand[c] > key) ? 1 : 0;
            if (rank < k) sel[rank] = key;
        }
    }
    __syncthreads();
    if (tid < 15) selk[((size_t)z * ROWS + row) * 16 + tid] = sel[tid];
}

// ---------- K3: apply boosts + record lists ----------
__global__ __launch_bounds__(64) void k_boost(
        const u64* __restrict__ selk,
        u64* __restrict__ basekeyR, u64* __restrict__ basekeyP,
        u32* __restrict__ plistP, u64* __restrict__ plistE, u32* __restrict__ pcnt,
        u32* __restrict__ plistP2, u64* __restrict__ plistE2, u32* __restrict__ pcnt2,
        int P, int ROWS) {
    int row = blockIdx.x, z = blockIdx.y, tid = threadIdx.x;
    int n = row >> 4, o = row & 15;
    u64* bkey = z ? basekeyP : basekeyR;
    u32* lp = z ? plistP2 : plistP;
    u64* le = z ? plistE2 : plistE;
    u32* lc = z ? pcnt2 : pcnt;
    const u64* src = selk + ((size_t)z * ROWS + row) * 16;

    __shared__ int sh_num;
    if (tid == 0) {
        float s = 0.0f; int pc = 0;
        #pragma unroll
        for (int j = 0; j < 15; j++) {
            float v = keyval(src[j]);
            s += v;
            if (v > 0.0f) pc++;
        }
        int np = (int)s; if (np < 1) np = 1;
        if (pc == 0) {
            u64 bk = ((u64)__float_as_uint(3.0f) << 32) | (u32)(~(u32)o);
            atomicMax(&bkey[(size_t)n * P + 0], bk);
            u32 idx = atomicAdd(&lc[n], 1u);
            lp[n * 256 + idx] = 0u;
            le[n * 256 + idx] = bk;
            sh_num = 0;
        } else {
            sh_num = np;
        }
    }
    __syncthreads();
    if (tid < 15 && tid < sh_num) {
        u64 kx = src[tid];
        float v = keyval(kx);
        if (v > 0.0f) {
            u32 pidx = ~(u32)(kx & 0xFFFFFFFFULL);
            u64 bk = ((u64)__float_as_uint(v + 3.0f) << 32) | (u32)(~(u32)o);
            atomicMax(&bkey[(size_t)n * P + pidx], bk);
            u32 idx = atomicAdd(&lc[n], 1u);
            lp[n * 256 + idx] = pidx;
            le[n * 256 + idx] = bk;
        }
    }
}

// ---------- K4: fused tail — gfocal corrections + posCount + localization loss ------
__global__ __launch_bounds__(256) void k_tail(
        const float* __restrict__ conf, const float* __restrict__ loc,
        const float* __restrict__ priors, const float* __restrict__ truths,
        const int* __restrict__ labels,
        const u64* __restrict__ bkeyR, const u64* __restrict__ bkeyP,
        const u32* __restrict__ plistP, const u64* __restrict__ plistE,
        const u32* __restrict__ pcnt,
        const u32* __restrict__ plistP2, const u64* __restrict__ plistE2,
        const u32* __restrict__ pcnt2,
        double* __restrict__ partCC, u32* __restrict__ posCnt,
        double* __restrict__ partL, double* __restrict__ partR, int P) {
    int n = blockIdx.x, tid = threadIdx.x;
    __shared__ int lab[16];
    __shared__ float strt[64];
    if (tid < 16) lab[tid] = labels[n * 16 + tid];
    if (tid < 64) strt[tid] = truths[n * 64 + tid];
    __syncthreads();

    int cnt = (int)pcnt[n];
    float dsum = 0.0f;
    int mypos = 0;
    for (int t = tid; t < cnt; t += 256) {
        u32 p = plistP[n * 256 + t];
        u64 bk = plistE[n * 256 + t];
        u64 kx = bkeyR[(size_t)n * P + p];
        if (kx == bk) {
            float v3 = keyval(kx);
            float vt = v3 - 3.0f;
            if (vt > 0.0f) {
                mypos++;
                int o = (int)(~(u32)(kx & 0xFFFFFFFFULL)) & 15;
                int tcls = lab[o];
                float lg = conf[((size_t)n * P + p) * 80 + tcls];
                float e  = fexp2(-fabsf(lg) * LOG2E);
                float ln1pe = flog2(1.0f + e) * LN2;
                float rc = frcp(1.0f + e);
                float sg = (lg >= 0.0f) ? rc : e * rc;
                float bce0 = fmaxf(lg, 0.0f) + ln1pe;
                float bce1 = fmaxf(lg, 0.0f) - lg * vt + ln1pe;
                float d1 = sg - vt;
                dsum += d1 * d1 * bce1 - sg * sg * bce0;
            }
        }
    }

    int cnt2 = (int)pcnt2[n];
    float rsum = 0.0f, csum = 0.0f;
    for (int t = tid; t < cnt2; t += 256) {
        u32 p = plistP2[n * 256 + t];
        u64 bk = plistE2[n * 256 + t];
        u64 kx = bkeyP[(size_t)n * P + p];
        if (kx == bk) {
            float pt = keyval(kx);
            float r = pt - 3.0f;
            if (r > 0.0f) {
                int best = (int)(~(u32)(kx & 0xFFFFFFFFULL)) & 15;
                const float Bc   = (float)19.085536923187668;
                const float beta = 0.11f;
                float4 pr = *(const float4*)(priors + (size_t)p * 4);
                float tx1 = strt[best * 4],     ty1 = strt[best * 4 + 1];
                float tx2 = strt[best * 4 + 2], ty2 = strt[best * 4 + 3];
                float gcx = ((tx1 + tx2) * 0.5f - pr.x) / (0.1f * pr.z);
                float gcy = ((ty1 + ty2) * 0.5f - pr.y) / (0.1f * pr.w);
                float gw  = flog2((tx2 - tx1) / pr.z) * LN2 / 0.2f;
                float gh  = flog2((ty2 - ty1) / pr.w) * LN2 / 0.2f;
                float4 l  = *(const float4*)(loc + ((size_t)n * P + p) * 4);
                float tgt[4] = {gcx, gcy, gw, gh};
                float lvv[4] = {l.x, l.y, l.z, l.w};
                float s = 0.0f;
                #pragma unroll
                for (int j = 0; j < 4; j++) {
                    float diff = fabsf(lvv[j] - tgt[j]);
                    float bl;
                    if (diff < beta) {
                        bl = 0.5f / Bc * (Bc * diff + 1.0f) *
                             (flog2(1.0f + Bc * diff / beta) * LN2) - 0.5f * diff;
                    } else {
                        bl = 1.5f * diff + 1.5f / Bc - 0.5f * beta;
                    }
                    s += bl;
                }
                rsum += r;
                csum += r * s;
            }
        }
    }

    double dd = (double)dsum, dl = (double)csum, dr = (double)rsum;
    long long pp = mypos;
    #pragma unroll
    for (int s = 32; s > 0; s >>= 1) {
        dd += __shfl_down(dd, s, 64);
        dl += __shfl_down(dl, s, 64);
        dr += __shfl_down(dr, s, 64);
        pp += __shfl_down(pp, s, 64);
    }
    __shared__ double wd[4], wl[4], wr[4];
    __shared__ long long wp[4];
    int wv = tid >> 6;
    if ((tid & 63) == 0) { wd[wv] = dd; wl[wv] = dl; wr[wv] = dr; wp[wv] = pp; }
    __syncthreads();
    if (tid == 0) {
        partCC[n] = wd[0] + wd[1] + wd[2] + wd[3];
        partL[n]  = wl[0] + wl[1] + wl[2] + wl[3];
        partR[n]  = wr[0] + wr[1] + wr[2] + wr[3];
        posCnt[n] = (u32)(wp[0] + wp[1] + wp[2] + wp[3]);
    }
}

// ---------- K5: final reduction ----------
__global__ __launch_bounds__(256) void k_fin(
        const double* __restrict__ partC, int nC, const double* __restrict__ partCC,
        const double* __restrict__ partL, const double* __restrict__ partR,
        const u32* __restrict__ posCnt, int N, float* __restrict__ out) {
    int tid = threadIdx.x;
    double sC = 0, sL = 0, sR = 0;
    long long pos = 0;
    for (int i = tid; i < nC; i += 256) sC += partC[i];
    for (int i = tid; i < N; i += 256) {
        sC += partCC[i]; sL += partL[i]; sR += partR[i];
        pos += (long long)posCnt[i];
    }
    #pragma unroll
    for (int s = 32; s > 0; s >>= 1) {
        sC += __shfl_down(sC, s, 64);
        sL += __shfl_down(sL, s, 64);
        sR += __shfl_down(sR, s, 64);
        pos += __shfl_down(pos, s, 64);
    }
    __shared__ double aC[4], aL[4], aR[4];
    __shared__ long long aP[4];
    int wv = tid >> 6;
    if ((tid & 63) == 0) { aC[wv] = sC; aL[wv] = sL; aR[wv] = sR; aP[wv] = pos; }
    __syncthreads();
    if (tid == 0) {
        double tC = aC[0] + aC[1] + aC[2] + aC[3];
        double tL = aL[0] + aL[1] + aL[2] + aL[3];
        double tR = aR[0] + aR[1] + aR[2] + aR[3];
        long long tP = aP[0] + aP[1] + aP[2] + aP[3];
        double npos = tP > 0 ? (double)tP : 1.0;
        out[0] = (float)(tL / (4.0 * tR));
        out[1] = (float)(tC / npos);
    }
}

extern "C" void kernel_launch(void* const* d_in, const int* in_sizes, int n_in,
                              void* d_out, int out_size, void* d_ws, size_t ws_size,
                              hipStream_t stream) {
    const float* loc    = (const float*)d_in[0];
    const float* conf   = (const float*)d_in[1];
    const float* priors = (const float*)d_in[2];
    const float* truths = (const float*)d_in[3];
    const int*   labels = (const int*)d_in[4];

    int P = in_sizes[2] / 4;                 // 18000
    int N = in_sizes[0] / (P * 4);           // 32
    int NBLK = (P + 63) / 64;                // 282
    int ROWS = N * 16;                       // 512
    int nC = NBLK * N;                       // 9024
    // C == 80, O == 16, P even assumed by kernel tiling

    char* cur = (char*)d_ws;
    auto alloc = [&](size_t bytes) { char* r = cur; cur += (bytes + 255) & ~(size_t)255; return r; };
    u32* pcnt      = (u32*)alloc((size_t)N * 4);
    u32* pcnt2     = (u32*)alloc((size_t)N * 4);
    u32* posCnt    = (u32*)alloc((size_t)N * 4);
    double* partCC = (double*)alloc((size_t)N * 8);
    u32* plistP    = (u32*)alloc((size_t)N * 256 * 4);
    u64* plistE    = (u64*)alloc((size_t)N * 256 * 8);
    u32* plistP2   = (u32*)alloc((size_t)N * 256 * 4);
    u64* plistE2   = (u64*)alloc((size_t)N * 256 * 8);
    double* partC  = (double*)alloc((size_t)nC * 8);
    double* partL  = (double*)alloc((size_t)N * 8);
    double* partR  = (double*)alloc((size_t)N * 8);
    u64* selk      = (u64*)alloc((size_t)2 * ROWS * 16 * 8);
    u64* basekeyR  = (u64*)alloc((size_t)N * P * 8);
    u64* basekeyP  = (u64*)alloc((size_t)N * P * 8);
    float* out = (float*)d_out;

    dim3 blk(256);
    dim3 gridB((NBLK + 3) / 4, N);
    dim3 gridS(ROWS, 2);

    k_main<<<gridB, blk, 0, stream>>>(loc, conf, priors, truths, labels,
                                      basekeyR, basekeyP, partC, pcnt, pcnt2, P, NBLK);
    k_sel<<<gridS, blk, 0, stream>>>(basekeyR, basekeyP, selk, P, ROWS);
    k_boost<<<gridS, 64, 0, stream>>>(selk, basekeyR, basekeyP,
                                      plistP, plistE, pcnt,
                                      plistP2, plistE2, pcnt2, P, ROWS);
    k_tail<<<N, blk, 0, stream>>>(conf, loc, priors, truths, labels,
                                  basekeyR, basekeyP,
                                  plistP, plistE, pcnt,
                                  plistP2, plistE2, pcnt2,
                                  partCC, posCnt, partL, partR, P);
    k_fin<<<1, blk, 0, stream>>>(partC, nC, partCC, partL, partR, posCnt, N, out);
}

// Round 20
// 132.086 us; speedup vs baseline: 1.0492x; 1.0492x over previous
//
#include <hip/hip_runtime.h>
#include <hip/hip_bf16.h>

typedef unsigned long long u64;
typedef unsigned int u32;

#define LOG2E 1.44269504088896340736f
#define LN2   0.69314718055994530942f
#define CAP   768

// ---------- fast math ----------
__device__ __forceinline__ float fexp2(float x) { return __builtin_amdgcn_exp2f(x); }
__device__ __forceinline__ float flog2(float x) { return __builtin_amdgcn_logf(x); }
__device__ __forceinline__ float frcp(float x)  { return __builtin_amdgcn_rcpf(x); }
__device__ __forceinline__ float keyval(u64 k) { return __uint_as_float((u32)(k >> 32)); }

__device__ __forceinline__ float iou_xyxy(float ax1, float ay1, float ax2, float ay2,
                                          float bx1, float by1, float bx2, float by2) {
    float ltx = fmaxf(ax1, bx1), lty = fmaxf(ay1, by1);
    float rbx = fminf(ax2, bx2), rby = fminf(ay2, by2);
    float w = fmaxf(rbx - ltx, 0.0f), h = fmaxf(rby - lty, 0.0f);
    float inter = w * h;
    float areaA = (ax2 - ax1) * (ay2 - ay1);
    float areaB = (bx2 - bx1) * (by2 - by1);
    return inter / (areaA + areaB - inter);
}

// ---------- K1: fused main pass; conf read FLAT-COALESCED (1 KB/instr/wave) ----------
__global__ __launch_bounds__(256) void k_main(
        const float* __restrict__ loc, const float* __restrict__ conf,
        const float* __restrict__ priors, const float* __restrict__ truths,
        const int* __restrict__ labels,
        u64* __restrict__ basekeyR, u64* __restrict__ basekeyP,
        double* __restrict__ partC, u32* __restrict__ pcnt, u32* __restrict__ pcnt2,
        int P) {
    int n = blockIdx.y, p0 = blockIdx.x * 64, tid = threadIdx.x;
    int r = tid >> 2, sub = tid & 3, p = p0 + r;
    bool act = p < P;
    int lane = tid & 63, wv = tid >> 6;
    int valid = P - p0; if (valid > 64) valid = 64;

    if (blockIdx.x == 0 && tid == 0) { pcnt[n] = 0u; pcnt2[n] = 0u; }

    // ---- flat conf loads: wave wv covers float4s [wv*320, wv*320+320) of this
    // block's 64 contiguous rows; lane i loads f4 = wv*320 + i + k*64 (contiguous/instr)
    const float4* cbase = (const float4*)(conf + ((size_t)n * P + p0) * 80);
    int f4base = wv * 320 + lane;
    int maxf4 = valid * 20;
    float4 C0, C1, C2, C3, C4, prv, lcv;
    C0 = C1 = C2 = C3 = C4 = prv = lcv = make_float4(0.f, 0.f, 0.f, 0.f);
    bool ca0 = f4base           < maxf4;
    bool ca1 = f4base + 64      < maxf4;
    bool ca2 = f4base + 128     < maxf4;
    bool ca3 = f4base + 192     < maxf4;
    bool ca4 = f4base + 256     < maxf4;
    if (ca0) C0 = cbase[f4base];
    if (ca1) C1 = cbase[f4base + 64];
    if (ca2) C2 = cbase[f4base + 128];
    if (ca3) C3 = cbase[f4base + 192];
    if (ca4) C4 = cbase[f4base + 256];
    if (act) {
        prv = *(const float4*)(priors + (size_t)p * 4);
        lcv = *(const float4*)(loc + ((size_t)n * P + p) * 4);
    }

    // per-chunk (row within block, class base) for the flat elements
    int rowk[5], clsk[5];
    #pragma unroll
    for (int k = 0; k < 5; k++) {
        int f4 = f4base + k * 64;
        rowk[k] = f4 / 20;
        clsk[k] = (f4 - rowk[k] * 20) * 4;
    }

    __shared__ float strt[64];
    __shared__ int   lab[16];
    __shared__ u32   smask[80];
    __shared__ float sglab[64][17];
    if (tid < 64) strt[tid] = truths[n * 64 + tid];
    if (tid < 80) smask[tid] = 0u;
    __syncthreads();
    if (tid < 16) {
        int lb = labels[n * 16 + tid];
        lab[tid] = lb;
        atomicOr(&smask[lb], 1u << tid);
    }
    __syncthreads();

    u32 mybits = 0;
    #pragma unroll
    for (int k = 0; k < 5; k++) {
        #pragma unroll
        for (int j = 0; j < 4; j++) {
            if (smask[clsk[k] + j]) mybits |= 1u << (k * 4 + j);
        }
    }

    // ---- reg path ((r,sub) mapping, unchanged)
    {
        float vv[4] = {0, 0, 0, 0};
        float vmax = 0.0f;
        if (act) {
            float cx = prv.x + lcv.x * 0.1f * prv.z;
            float cy = prv.y + lcv.y * 0.1f * prv.w;
            float w  = prv.z * fexp2(lcv.z * 0.2f * LOG2E);
            float h  = prv.w * fexp2(lcv.w * 0.2f * LOG2E);
            float bx1 = cx - w * 0.5f, by1 = cy - h * 0.5f;
            float bx2 = cx + w * 0.5f, by2 = cy + h * 0.5f;
            #pragma unroll
            for (int jj = 0; jj < 4; jj++) {
                int o = sub * 4 + jj;
                float v = iou_xyxy(strt[o * 4], strt[o * 4 + 1], strt[o * 4 + 2],
                                   strt[o * 4 + 3], bx1, by1, bx2, by2);
                vv[jj] = v;
                vmax = fmaxf(vmax, v);
            }
        }
        vmax = fmaxf(vmax, __shfl_xor(vmax, 1, 64));
        vmax = fmaxf(vmax, __shfl_xor(vmax, 2, 64));
        u32 bits = 0;
        #pragma unroll
        for (int jj = 0; jj < 4; jj++) {
            if (act && vv[jj] == vmax) bits |= 1u << (sub * 4 + jj);
        }
        bits |= __shfl_xor(bits, 1, 64);
        bits |= __shfl_xor(bits, 2, 64);
        if (act && sub == 0) {
            basekeyR[(size_t)n * P + p] = ((u64)__float_as_uint(vmax) << 32) | bits;
        }
    }

    // ---- gfocal over flat elements, t = 0 everywhere; capture label sigmoids
    float lsum = 0.0f;
    {
        float4 CC[5] = {C0, C1, C2, C3, C4};
        bool cact[5] = {ca0, ca1, ca2, ca3, ca4};
        #pragma unroll
        for (int k = 0; k < 5; k++) {
            if (cact[k]) {
                float lvv[4] = {CC[k].x, CC[k].y, CC[k].z, CC[k].w};
                #pragma unroll
                for (int j = 0; j < 4; j++) {
                    float lg = lvv[j];
                    float e  = fexp2(-fabsf(lg) * LOG2E);
                    float ln1pe = flog2(1.0f + e) * LN2;
                    float rc = frcp(1.0f + e);
                    float sg = (lg >= 0.0f) ? rc : e * rc;
                    lsum += sg * sg * (fmaxf(lg, 0.0f) + ln1pe);
                    if (mybits & (1u << (k * 4 + j))) {
                        u32 m16 = smask[clsk[k] + j];
                        while (m16) {
                            int o = __ffs(m16) - 1;
                            sglab[rowk[k]][o] = sg;
                            m16 &= m16 - 1;
                        }
                    }
                }
            }
        }
    }
    __syncthreads();

    // ---- pred path ((r,sub) mapping, unchanged)
    {
        float pv[4] = {0, 0, 0, 0};
        float pmax = 0.0f;
        if (act) {
            float px1 = prv.x - prv.z * 0.5f, py1 = prv.y - prv.w * 0.5f;
            float px2 = prv.x + prv.z * 0.5f, py2 = prv.y + prv.w * 0.5f;
            #pragma unroll
            for (int jj = 0; jj < 4; jj++) {
                int o = sub * 4 + jj;
                float ov = iou_xyxy(strt[o * 4], strt[o * 4 + 1], strt[o * 4 + 2],
                                    strt[o * 4 + 3], px1, py1, px2, py2);
                float pd = 0.0f;
                if (ov > 0.0f) {
                    float pc = sglab[r][o];
                    pd = fexp2((2.0f - pc) * 0.5f * flog2(ov));
                }
                pv[jj] = pd;
                pmax = fmaxf(pmax, pd);
            }
        }
        pmax = fmaxf(pmax, __shfl_xor(pmax, 1, 64));
        pmax = fmaxf(pmax, __shfl_xor(pmax, 2, 64));
        u32 bits = 0;
        #pragma unroll
        for (int jj = 0; jj < 4; jj++) {
            if (act && pv[jj] == pmax) bits |= 1u << (sub * 4 + jj);
        }
        bits |= __shfl_xor(bits, 1, 64);
        bits |= __shfl_xor(bits, 2, 64);
        if (act && sub == 0) {
            basekeyP[(size_t)n * P + p] = ((u64)__float_as_uint(pmax) << 32) | bits;
        }
    }

    #pragma unroll
    for (int s = 32; s > 0; s >>= 1) lsum += __shfl_down(lsum, s, 64);
    __shared__ float wsum[4];
    if ((tid & 63) == 0) wsum[tid >> 6] = lsum;
    __syncthreads();
    if (tid == 0) {
        partC[(size_t)blockIdx.y * gridDim.x + blockIdx.x] =
            (double)wsum[0] + (double)wsum[1] + (double)wsum[2] + (double)wsum[3];
    }
}

// ---------- K2: per-(row,z) exact top-15 via histogram radix-select ----------
__global__ __launch_bounds__(256) void k_sel(
        const u64* __restrict__ basekeyR, const u64* __restrict__ basekeyP,
        u64* __restrict__ selk, int P, int ROWS) {
    int row = blockIdx.x, z = blockIdx.y, tid = threadIdx.x;
    int n = row >> 4, o = row & 15;
    const u64* base = (z ? basekeyP : basekeyR) + (size_t)n * P;

    __shared__ u32 hist[2048];
    __shared__ u32 tsum[256];
    __shared__ int sB;
    __shared__ u32 sSB;
    __shared__ u32 sT;
    __shared__ u64 cand[CAP];
    __shared__ u32 scnt;
    __shared__ u64 sel[15];

    if (tid == 0) scnt = 0u;
    if (tid < 15) sel[tid] = 0ULL;

    u64 pmask = 0, pval = 0;
    int shift = 53;
    int k = 0;
    int need = 15;
    bool done = false;

    for (int lvl = 0; lvl < 3 && !done; lvl++) {
        #pragma unroll
        for (int i = 0; i < 8; i++) hist[tid + i * 256] = 0u;
        __syncthreads();
        for (int i = tid * 2; i < P; i += 512) {
            ulonglong2 v = *(const ulonglong2*)(base + i);
            u64 b0 = v.x, b1 = v.y;
            if ((u32)(b0 >> 32) != 0u && ((b0 >> o) & 1) && (b0 & pmask) == pval)
                atomicAdd(&hist[(u32)(b0 >> shift) & 2047u], 1u);
            if ((u32)(b1 >> 32) != 0u && ((b1 >> o) & 1) && (b1 & pmask) == pval)
                atomicAdd(&hist[(u32)(b1 >> shift) & 2047u], 1u);
        }
        __syncthreads();
        u32 l_[8], ls[8];
        #pragma unroll
        for (int i = 0; i < 8; i++) l_[i] = hist[tid * 8 + i];
        ls[7] = l_[7];
        #pragma unroll
        for (int i = 6; i >= 0; i--) ls[i] = ls[i + 1] + l_[i];
        tsum[tid] = ls[0];
        __syncthreads();
        for (int d = 1; d < 256; d <<= 1) {
            u32 v = (tid + d < 256) ? tsum[tid + d] : 0u;
            __syncthreads();
            tsum[tid] += v;
            __syncthreads();
        }
        if (lvl == 0) {
            if (tid == 0) sT = tsum[0];
            __syncthreads();
            u32 T = sT;
            if (T == 0u) { k = 0; break; }
            k = (T < 15u) ? (int)T : 15;
            need = k;
        }
        u32 off = (tid < 255) ? tsum[tid + 1] : 0u;
        int myB = -1;
        #pragma unroll
        for (int i = 0; i < 8; i++) {
            u32 S = ls[i] + off;
            if ((int)S >= need) { int b = tid * 8 + i; if (b > myB) myB = b; }
        }
        if (tid == 0) sB = -1;
        __syncthreads();
        if (myB >= 0) atomicMax(&sB, myB);
        __syncthreads();
        int B = sB;
        if (B >= 0 && (B >> 3) == tid) sSB = ls[B & 7] + off;
        __syncthreads();
        u32 SB = sSB;
        bool last = (lvl == 2);
        bool fits = ((scnt + SB) <= (u32)CAP) || last;
        for (int i = tid * 2; i < P; i += 512) {
            ulonglong2 v = *(const ulonglong2*)(base + i);
            #pragma unroll
            for (int j = 0; j < 2; j++) {
                u64 b = (j == 0) ? v.x : v.y;
                int pp = i + j;
                if ((u32)(b >> 32) != 0u && ((b >> o) & 1) && (b & pmask) == pval) {
                    int bin = (int)((u32)(b >> shift) & 2047u);
                    bool take = fits ? (bin >= B) : (bin > B);
                    if (take) {
                        u32 idx = atomicAdd(&scnt, 1u);
                        if (idx < (u32)CAP)
                            cand[idx] = (b & 0xFFFFFFFF00000000ULL) | (u32)(~(u32)pp);
                    }
                }
            }
        }
        __syncthreads();
        if (fits) {
            done = true;
        } else {
            need = k - (int)scnt;
            pmask |= (u64)2047u << shift;
            pval |= ((u64)(u32)B) << shift;
            shift -= 11;
            __syncthreads();
        }
    }

    __syncthreads();
    if (k > 0) {
        u32 cnt = scnt; if (cnt > (u32)CAP) cnt = (u32)CAP;
        for (u32 i = tid; i < cnt; i += 256) {
            u64 key = cand[i];
            int rank = 0;
            for (u32 c = 0; c < cnt; c++) rank += (cand[c] > key) ? 1 : 0;
            if (rank < k) sel[rank] = key;
        }
    }
    __syncthreads();
    if (tid < 15) selk[((size_t)z * ROWS + row) * 16 + tid] = sel[tid];
}

// ---------- K3: apply boosts + record lists ----------
__global__ __launch_bounds__(64) void k_boost(
        const u64* __restrict__ selk,
        u64* __restrict__ basekeyR, u64* __restrict__ basekeyP,
        u32* __restrict__ plistP, u64* __restrict__ plistE, u32* __restrict__ pcnt,
        u32* __restrict__ plistP2, u64* __restrict__ plistE2, u32* __restrict__ pcnt2,
        int P, int ROWS) {
    int row = blockIdx.x, z = blockIdx.y, tid = threadIdx.x;
    int n = row >> 4, o = row & 15;
    u64* bkey = z ? basekeyP : basekeyR;
    u32* lp = z ? plistP2 : plistP;
    u64* le = z ? plistE2 : plistE;
    u32* lc = z ? pcnt2 : pcnt;
    const u64* src = selk + ((size_t)z * ROWS + row) * 16;

    __shared__ int sh_num;
    if (tid == 0) {
        float s = 0.0f; int pc = 0;
        #pragma unroll
        for (int j = 0; j < 15; j++) {
            float v = keyval(src[j]);
            s += v;
            if (v > 0.0f) pc++;
        }
        int np = (int)s; if (np < 1) np = 1;
        if (pc == 0) {
            u64 bk = ((u64)__float_as_uint(3.0f) << 32) | (u32)(~(u32)o);
            atomicMax(&bkey[(size_t)n * P + 0], bk);
            u32 idx = atomicAdd(&lc[n], 1u);
            lp[n * 256 + idx] = 0u;
            le[n * 256 + idx] = bk;
            sh_num = 0;
        } else {
            sh_num = np;
        }
    }
    __syncthreads();
    if (tid < 15 && tid < sh_num) {
        u64 kx = src[tid];
        float v = keyval(kx);
        if (v > 0.0f) {
            u32 pidx = ~(u32)(kx & 0xFFFFFFFFULL);
            u64 bk = ((u64)__float_as_uint(v + 3.0f) << 32) | (u32)(~(u32)o);
            atomicMax(&bkey[(size_t)n * P + pidx], bk);
            u32 idx = atomicAdd(&lc[n], 1u);
            lp[n * 256 + idx] = pidx;
            le[n * 256 + idx] = bk;
        }
    }
}

// ---------- K4: fused tail — gfocal corrections + posCount + localization loss ------
__global__ __launch_bounds__(256) void k_tail(
        const float* __restrict__ conf, const float* __restrict__ loc,
        const float* __restrict__ priors, const float* __restrict__ truths,
        const int* __restrict__ labels,
        const u64* __restrict__ bkeyR, const u64* __restrict__ bkeyP,
        const u32* __restrict__ plistP, const u64* __restrict__ plistE,
        const u32* __restrict__ pcnt,
        const u32* __restrict__ plistP2, const u64* __restrict__ plistE2,
        const u32* __restrict__ pcnt2,
        double* __restrict__ partCC, u32* __restrict__ posCnt,
        double* __restrict__ partL, double* __restrict__ partR, int P) {
    int n = blockIdx.x, tid = threadIdx.x;
    __shared__ int lab[16];
    __shared__ float strt[64];
    if (tid < 16) lab[tid] = labels[n * 16 + tid];
    if (tid < 64) strt[tid] = truths[n * 64 + tid];
    __syncthreads();

    int cnt = (int)pcnt[n];
    float dsum = 0.0f;
    int mypos = 0;
    for (int t = tid; t < cnt; t += 256) {
        u32 p = plistP[n * 256 + t];
        u64 bk = plistE[n * 256 + t];
        u64 kx = bkeyR[(size_t)n * P + p];
        if (kx == bk) {
            float v3 = keyval(kx);
            float vt = v3 - 3.0f;
            if (vt > 0.0f) {
                mypos++;
                int o = (int)(~(u32)(kx & 0xFFFFFFFFULL)) & 15;
                int tcls = lab[o];
                float lg = conf[((size_t)n * P + p) * 80 + tcls];
                float e  = fexp2(-fabsf(lg) * LOG2E);
                float ln1pe = flog2(1.0f + e) * LN2;
                float rc = frcp(1.0f + e);
                float sg = (lg >= 0.0f) ? rc : e * rc;
                float bce0 = fmaxf(lg, 0.0f) + ln1pe;
                float bce1 = fmaxf(lg, 0.0f) - lg * vt + ln1pe;
                float d1 = sg - vt;
                dsum += d1 * d1 * bce1 - sg * sg * bce0;
            }
        }
    }

    int cnt2 = (int)pcnt2[n];
    float rsum = 0.0f, csum = 0.0f;
    for (int t = tid; t < cnt2; t += 256) {
        u32 p = plistP2[n * 256 + t];
        u64 bk = plistE2[n * 256 + t];
        u64 kx = bkeyP[(size_t)n * P + p];
        if (kx == bk) {
            float pt = keyval(kx);
            float r = pt - 3.0f;
            if (r > 0.0f) {
                int best = (int)(~(u32)(kx & 0xFFFFFFFFULL)) & 15;
                const float Bc   = (float)19.085536923187668;
                const float beta = 0.11f;
                float4 pr = *(const float4*)(priors + (size_t)p * 4);
                float tx1 = strt[best * 4],     ty1 = strt[best * 4 + 1];
                float tx2 = strt[best * 4 + 2], ty2 = strt[best * 4 + 3];
                float gcx = ((tx1 + tx2) * 0.5f - pr.x) / (0.1f * pr.z);
                float gcy = ((ty1 + ty2) * 0.5f - pr.y) / (0.1f * pr.w);
                float gw  = flog2((tx2 - tx1) / pr.z) * LN2 / 0.2f;
                float gh  = flog2((ty2 - ty1) / pr.w) * LN2 / 0.2f;
                float4 l  = *(const float4*)(loc + ((size_t)n * P + p) * 4);
                float tgt[4] = {gcx, gcy, gw, gh};
                float lvv[4] = {l.x, l.y, l.z, l.w};
                float s = 0.0f;
                #pragma unroll
                for (int j = 0; j < 4; j++) {
                    float diff = fabsf(lvv[j] - tgt[j]);
                    float bl;
                    if (diff < beta) {
                        bl = 0.5f / Bc * (Bc * diff + 1.0f) *
                             (flog2(1.0f + Bc * diff / beta) * LN2) - 0.5f * diff;
                    } else {
                        bl = 1.5f * diff + 1.5f / Bc - 0.5f * beta;
                    }
                    s += bl;
                }
                rsum += r;
                csum += r * s;
            }
        }
    }

    double dd = (double)dsum, dl = (double)csum, dr = (double)rsum;
    long long pp = mypos;
    #pragma unroll
    for (int s = 32; s > 0; s >>= 1) {
        dd += __shfl_down(dd, s, 64);
        dl += __shfl_down(dl, s, 64);
        dr += __shfl_down(dr, s, 64);
        pp += __shfl_down(pp, s, 64);
    }
    __shared__ double wd[4], wl[4], wr[4];
    __shared__ long long wp[4];
    int wv = tid >> 6;
    if ((tid & 63) == 0) { wd[wv] = dd; wl[wv] = dl; wr[wv] = dr; wp[wv] = pp; }
    __syncthreads();
    if (tid == 0) {
        partCC[n] = wd[0] + wd[1] + wd[2] + wd[3];
        partL[n]  = wl[0] + wl[1] + wl[2] + wl[3];
        partR[n]  = wr[0] + wr[1] + wr[2] + wr[3];
        posCnt[n] = (u32)(wp[0] + wp[1] + wp[2] + wp[3]);
    }
}

// ---------- K5: final reduction ----------
__global__ __launch_bounds__(256) void k_fin(
        const double* __restrict__ partC, int nC, const double* __restrict__ partCC,
        const double* __restrict__ partL, const double* __restrict__ partR,
        const u32* __restrict__ posCnt, int N, float* __restrict__ out) {
    int tid = threadIdx.x;
    double sC = 0, sL = 0, sR = 0;
    long long pos = 0;
    for (int i = tid; i < nC; i += 256) sC += partC[i];
    for (int i = tid; i < N; i += 256) {
        sC += partCC[i]; sL += partL[i]; sR += partR[i];
        pos += (long long)posCnt[i];
    }
    #pragma unroll
    for (int s = 32; s > 0; s >>= 1) {
        sC += __shfl_down(sC, s, 64);
        sL += __shfl_down(sL, s, 64);
        sR += __shfl_down(sR, s, 64);
        pos += __shfl_down(pos, s, 64);
    }
    __shared__ double aC[4], aL[4], aR[4];
    __shared__ long long aP[4];
    int wv = tid >> 6;
    if ((tid & 63) == 0) { aC[wv] = sC; aL[wv] = sL; aR[wv] = sR; aP[wv] = pos; }
    __syncthreads();
    if (tid == 0) {
        double tC = aC[0] + aC[1] + aC[2] + aC[3];
        double tL = aL[0] + aL[1] + aL[2] + aL[3];
        double tR = aR[0] + aR[1] + aR[2] + aR[3];
        long long tP = aP[0] + aP[1] + aP[2] + aP[3];
        double npos = tP > 0 ? (double)tP : 1.0;
        out[0] = (float)(tL / (4.0 * tR));
        out[1] = (float)(tC / npos);
    }
}

extern "C" void kernel_launch(void* const* d_in, const int* in_sizes, int n_in,
                              void* d_out, int out_size, void* d_ws, size_t ws_size,
                              hipStream_t stream) {
    const float* loc    = (const float*)d_in[0];
    const float* conf   = (const float*)d_in[1];
    const float* priors = (const float*)d_in[2];
    const float* truths = (const float*)d_in[3];
    const int*   labels = (const int*)d_in[4];

    int P = in_sizes[2] / 4;                 // 18000
    int N = in_sizes[0] / (P * 4);           // 32
    int NBLK = (P + 63) / 64;                // 282
    int ROWS = N * 16;                       // 512
    int nC = NBLK * N;                       // 9024
    // C == 80, O == 16, P even assumed by kernel tiling

    char* cur = (char*)d_ws;
    auto alloc = [&](size_t bytes) { char* r = cur; cur += (bytes + 255) & ~(size_t)255; return r; };
    u32* pcnt      = (u32*)alloc((size_t)N * 4);
    u32* pcnt2     = (u32*)alloc((size_t)N * 4);
    u32* posCnt    = (u32*)alloc((size_t)N * 4);
    double* partCC = (double*)alloc((size_t)N * 8);
    u32* plistP    = (u32*)alloc((size_t)N * 256 * 4);
    u64* plistE    = (u64*)alloc((size_t)N * 256 * 8);
    u32* plistP2   = (u32*)alloc((size_t)N * 256 * 4);
    u64* plistE2   = (u64*)alloc((size_t)N * 256 * 8);
    double* partC  = (double*)alloc((size_t)nC * 8);
    double* partL  = (double*)alloc((size_t)N * 8);
    double* partR  = (double*)alloc((size_t)N * 8);
    u64* selk      = (u64*)alloc((size_t)2 * ROWS * 16 * 8);
    u64* basekeyR  = (u64*)alloc((size_t)N * P * 8);
    u64* basekeyP  = (u64*)alloc((size_t)N * P * 8);
    float* out = (float*)d_out;

    dim3 blk(256);
    dim3 gridB(NBLK, N);
    dim3 gridS(ROWS, 2);

    k_main<<<gridB, blk, 0, stream>>>(loc, conf, priors, truths, labels,
                                      basekeyR, basekeyP, partC, pcnt, pcnt2, P);
    k_sel<<<gridS, blk, 0, stream>>>(basekeyR, basekeyP, selk, P, ROWS);
    k_boost<<<gridS, 64, 0, stream>>>(selk, basekeyR, basekeyP,
                                      plistP, plistE, pcnt,
                                      plistP2, plistE2, pcnt2, P, ROWS);
    k_tail<<<N, blk, 0, stream>>>(conf, loc, priors, truths, labels,
                                  basekeyR, basekeyP,
                                  plistP, plistE, pcnt,
                                  plistP2, plistE2, pcnt2,
                                  partCC, posCnt, partL, partR, P);
    k_fin<<<1, blk, 0, stream>>>(partC, nC, partCC, partL, partR, posCnt, N, out);
}

// Round 21
// 125.951 us; speedup vs baseline: 1.1003x; 1.0487x over previous
//
#include <hip/hip_runtime.h>
#include <hip/hip_bf16.h>

typedef unsigned long long u64;
typedef unsigned int u32;

#define LOG2E 1.44269504088896340736f
#define LN2   0.69314718055994530942f
#define CAP   768

// ---------- fast math ----------
__device__ __forceinline__ float fexp2(float x) { return __builtin_amdgcn_exp2f(x); }
__device__ __forceinline__ float flog2(float x) { return __builtin_amdgcn_logf(x); }
__device__ __forceinline__ float frcp(float x)  { return __builtin_amdgcn_rcpf(x); }
__device__ __forceinline__ float keyval(u64 k) { return __uint_as_float((u32)(k >> 32)); }

__device__ __forceinline__ float iou_xyxy(float ax1, float ay1, float ax2, float ay2,
                                          float bx1, float by1, float bx2, float by2) {
    float ltx = fmaxf(ax1, bx1), lty = fmaxf(ay1, by1);
    float rbx = fminf(ax2, bx2), rby = fminf(ay2, by2);
    float w = fmaxf(rbx - ltx, 0.0f), h = fmaxf(rby - lty, 0.0f);
    float inter = w * h;
    float areaA = (ax2 - ax1) * (ay2 - ay1);
    float areaB = (bx2 - bx1) * (by2 - by1);
    return inter / (areaA + areaB - inter);
}

// ---------- K1: fused main pass (reg path + gfocal stream + pred path) ----------
__global__ __launch_bounds__(256) void k_main(
        const float* __restrict__ loc, const float* __restrict__ conf,
        const float* __restrict__ priors, const float* __restrict__ truths,
        const int* __restrict__ labels,
        u64* __restrict__ basekeyR, u64* __restrict__ basekeyP,
        double* __restrict__ partC, u32* __restrict__ pcnt, u32* __restrict__ pcnt2,
        int P) {
    int n = blockIdx.y, p0 = blockIdx.x * 64, tid = threadIdx.x;
    int r = tid >> 2, sub = tid & 3, p = p0 + r;
    bool act = p < P;

    if (blockIdx.x == 0 && tid == 0) { pcnt[n] = 0u; pcnt2[n] = 0u; }

    float4 L0, L1, L2, L3, L4, prv, lc;
    L0 = L1 = L2 = L3 = L4 = prv = lc = make_float4(0.f, 0.f, 0.f, 0.f);
    if (act) {
        const float* rowp = conf + ((size_t)n * P + p) * 80 + sub * 4;
        L0 = *(const float4*)(rowp);
        L1 = *(const float4*)(rowp + 16);
        L2 = *(const float4*)(rowp + 32);
        L3 = *(const float4*)(rowp + 48);
        L4 = *(const float4*)(rowp + 64);
        prv = *(const float4*)(priors + (size_t)p * 4);
        lc  = *(const float4*)(loc + ((size_t)n * P + p) * 4);
    }

    __shared__ float strt[64];
    __shared__ int   lab[16];
    __shared__ u32   smask[80];
    __shared__ float sglab[64][17];
    if (tid < 64) strt[tid] = truths[n * 64 + tid];
    if (tid < 80) smask[tid] = 0u;
    __syncthreads();
    if (tid < 16) {
        int lb = labels[n * 16 + tid];
        lab[tid] = lb;
        atomicOr(&smask[lb], 1u << tid);
    }
    __syncthreads();

    u32 mybits = 0;
    #pragma unroll
    for (int k = 0; k < 5; k++) {
        #pragma unroll
        for (int j = 0; j < 4; j++) {
            if (smask[k * 16 + sub * 4 + j]) mybits |= 1u << (k * 4 + j);
        }
    }

    // ---- reg path
    {
        float vv[4] = {0, 0, 0, 0};
        float vmax = 0.0f;
        if (act) {
            float cx = prv.x + lc.x * 0.1f * prv.z;
            float cy = prv.y + lc.y * 0.1f * prv.w;
            float w  = prv.z * fexp2(lc.z * 0.2f * LOG2E);
            float h  = prv.w * fexp2(lc.w * 0.2f * LOG2E);
            float bx1 = cx - w * 0.5f, by1 = cy - h * 0.5f;
            float bx2 = cx + w * 0.5f, by2 = cy + h * 0.5f;
            #pragma unroll
            for (int jj = 0; jj < 4; jj++) {
                int o = sub * 4 + jj;
                float v = iou_xyxy(strt[o * 4], strt[o * 4 + 1], strt[o * 4 + 2],
                                   strt[o * 4 + 3], bx1, by1, bx2, by2);
                vv[jj] = v;
                vmax = fmaxf(vmax, v);
            }
        }
        vmax = fmaxf(vmax, __shfl_xor(vmax, 1, 64));
        vmax = fmaxf(vmax, __shfl_xor(vmax, 2, 64));
        u32 bits = 0;
        #pragma unroll
        for (int jj = 0; jj < 4; jj++) {
            if (act && vv[jj] == vmax) bits |= 1u << (sub * 4 + jj);
        }
        bits |= __shfl_xor(bits, 1, 64);
        bits |= __shfl_xor(bits, 2, 64);
        if (act && sub == 0) {
            basekeyR[(size_t)n * P + p] = ((u64)__float_as_uint(vmax) << 32) | bits;
        }
    }

    // ---- gfocal stream, t = 0 everywhere
    float lsum = 0.0f;
    if (act) {
        float lv[20] = {L0.x, L0.y, L0.z, L0.w, L1.x, L1.y, L1.z, L1.w,
                        L2.x, L2.y, L2.z, L2.w, L3.x, L3.y, L3.z, L3.w,
                        L4.x, L4.y, L4.z, L4.w};
        #pragma unroll
        for (int k = 0; k < 5; k++) {
            #pragma unroll
            for (int j = 0; j < 4; j++) {
                float lg = lv[k * 4 + j];
                float e  = fexp2(-fabsf(lg) * LOG2E);
                float ln1pe = flog2(1.0f + e) * LN2;
                float rc = frcp(1.0f + e);
                float sg = (lg >= 0.0f) ? rc : e * rc;
                lsum += sg * sg * (fmaxf(lg, 0.0f) + ln1pe);
                if (mybits & (1u << (k * 4 + j))) {
                    u32 m16 = smask[k * 16 + sub * 4 + j];
                    while (m16) {
                        int o = __ffs(m16) - 1;
                        sglab[r][o] = sg;
                        m16 &= m16 - 1;
                    }
                }
            }
        }
    }
    __syncthreads();

    // ---- pred path
    {
        float pv[4] = {0, 0, 0, 0};
        float pmax = 0.0f;
        if (act) {
            float px1 = prv.x - prv.z * 0.5f, py1 = prv.y - prv.w * 0.5f;
            float px2 = prv.x + prv.z * 0.5f, py2 = prv.y + prv.w * 0.5f;
            #pragma unroll
            for (int jj = 0; jj < 4; jj++) {
                int o = sub * 4 + jj;
                float ov = iou_xyxy(strt[o * 4], strt[o * 4 + 1], strt[o * 4 + 2],
                                    strt[o * 4 + 3], px1, py1, px2, py2);
                float pd = 0.0f;
                if (ov > 0.0f) {
                    float pc = sglab[r][o];
                    pd = fexp2((2.0f - pc) * 0.5f * flog2(ov));
                }
                pv[jj] = pd;
                pmax = fmaxf(pmax, pd);
            }
        }
        pmax = fmaxf(pmax, __shfl_xor(pmax, 1, 64));
        pmax = fmaxf(pmax, __shfl_xor(pmax, 2, 64));
        u32 bits = 0;
        #pragma unroll
        for (int jj = 0; jj < 4; jj++) {
            if (act && pv[jj] == pmax) bits |= 1u << (sub * 4 + jj);
        }
        bits |= __shfl_xor(bits, 1, 64);
        bits |= __shfl_xor(bits, 2, 64);
        if (act && sub == 0) {
            basekeyP[(size_t)n * P + p] = ((u64)__float_as_uint(pmax) << 32) | bits;
        }
    }

    #pragma unroll
    for (int s = 32; s > 0; s >>= 1) lsum += __shfl_down(lsum, s, 64);
    __shared__ float wsum[4];
    if ((tid & 63) == 0) wsum[tid >> 6] = lsum;
    __syncthreads();
    if (tid == 0) {
        partC[(size_t)blockIdx.y * gridDim.x + blockIdx.x] =
            (double)wsum[0] + (double)wsum[1] + (double)wsum[2] + (double)wsum[3];
    }
}

// ---------- K2: per-(row,z) exact top-15 via histogram radix-select ----------
__global__ __launch_bounds__(256) void k_sel(
        const u64* __restrict__ basekeyR, const u64* __restrict__ basekeyP,
        u64* __restrict__ selk, int P, int ROWS) {
    int row = blockIdx.x, z = blockIdx.y, tid = threadIdx.x;
    int n = row >> 4, o = row & 15;
    const u64* base = (z ? basekeyP : basekeyR) + (size_t)n * P;

    __shared__ u32 hist[2048];
    __shared__ u32 tsum[256];
    __shared__ int sB;
    __shared__ u32 sSB;
    __shared__ u32 sT;
    __shared__ u64 cand[CAP];
    __shared__ u32 scnt;
    __shared__ u64 sel[15];

    if (tid == 0) scnt = 0u;
    if (tid < 15) sel[tid] = 0ULL;

    u64 pmask = 0, pval = 0;
    int shift = 53;
    int k = 0;
    int need = 15;
    bool done = false;

    for (int lvl = 0; lvl < 3 && !done; lvl++) {
        #pragma unroll
        for (int i = 0; i < 8; i++) hist[tid + i * 256] = 0u;
        __syncthreads();
        for (int i = tid * 2; i < P; i += 512) {
            ulonglong2 v = *(const ulonglong2*)(base + i);
            u64 b0 = v.x, b1 = v.y;
            if ((u32)(b0 >> 32) != 0u && ((b0 >> o) & 1) && (b0 & pmask) == pval)
                atomicAdd(&hist[(u32)(b0 >> shift) & 2047u], 1u);
            if ((u32)(b1 >> 32) != 0u && ((b1 >> o) & 1) && (b1 & pmask) == pval)
                atomicAdd(&hist[(u32)(b1 >> shift) & 2047u], 1u);
        }
        __syncthreads();
        u32 l_[8], ls[8];
        #pragma unroll
        for (int i = 0; i < 8; i++) l_[i] = hist[tid * 8 + i];
        ls[7] = l_[7];
        #pragma unroll
        for (int i = 6; i >= 0; i--) ls[i] = ls[i + 1] + l_[i];
        tsum[tid] = ls[0];
        __syncthreads();
        for (int d = 1; d < 256; d <<= 1) {
            u32 v = (tid + d < 256) ? tsum[tid + d] : 0u;
            __syncthreads();
            tsum[tid] += v;
            __syncthreads();
        }
        if (lvl == 0) {
            if (tid == 0) sT = tsum[0];
            __syncthreads();
            u32 T = sT;
            if (T == 0u) { k = 0; break; }
            k = (T < 15u) ? (int)T : 15;
            need = k;
        }
        u32 off = (tid < 255) ? tsum[tid + 1] : 0u;
        int myB = -1;
        #pragma unroll
        for (int i = 0; i < 8; i++) {
            u32 S = ls[i] + off;
            if ((int)S >= need) { int b = tid * 8 + i; if (b > myB) myB = b; }
        }
        if (tid == 0) sB = -1;
        __syncthreads();
        if (myB >= 0) atomicMax(&sB, myB);
        __syncthreads();
        int B = sB;
        if (B >= 0 && (B >> 3) == tid) sSB = ls[B & 7] + off;
        __syncthreads();
        u32 SB = sSB;
        bool last = (lvl == 2);
        bool fits = ((scnt + SB) <= (u32)CAP) || last;
        for (int i = tid * 2; i < P; i += 512) {
            ulonglong2 v = *(const ulonglong2*)(base + i);
            #pragma unroll
            for (int j = 0; j < 2; j++) {
                u64 b = (j == 0) ? v.x : v.y;
                int pp = i + j;
                if ((u32)(b >> 32) != 0u && ((b >> o) & 1) && (b & pmask) == pval) {
                    int bin = (int)((u32)(b >> shift) & 2047u);
                    bool take = fits ? (bin >= B) : (bin > B);
                    if (take) {
                        u32 idx = atomicAdd(&scnt, 1u);
                        if (idx < (u32)CAP)
                            cand[idx] = (b & 0xFFFFFFFF00000000ULL) | (u32)(~(u32)pp);
                    }
                }
            }
        }
        __syncthreads();
        if (fits) {
            done = true;
        } else {
            need = k - (int)scnt;
            pmask |= (u64)2047u << shift;
            pval |= ((u64)(u32)B) << shift;
            shift -= 11;
            __syncthreads();
        }
    }

    __syncthreads();
    if (k > 0) {
        u32 cnt = scnt; if (cnt > (u32)CAP) cnt = (u32)CAP;
        for (u32 i = tid; i < cnt; i += 256) {
            u64 key = cand[i];
            int rank = 0;
            for (u32 c = 0; c < cnt; c++) rank += (cand[c] > key) ? 1 : 0;
            if (rank < k) sel[rank] = key;
        }
    }
    __syncthreads();
    if (tid < 15) selk[((size_t)z * ROWS + row) * 16 + tid] = sel[tid];
}

// ---------- K3: apply boosts + record lists ----------
__global__ __launch_bounds__(64) void k_boost(
        const u64* __restrict__ selk,
        u64* __restrict__ basekeyR, u64* __restrict__ basekeyP,
        u32* __restrict__ plistP, u64* __restrict__ plistE, u32* __restrict__ pcnt,
        u32* __restrict__ plistP2, u64* __restrict__ plistE2, u32* __restrict__ pcnt2,
        int P, int ROWS) {
    int row = blockIdx.x, z = blockIdx.y, tid = threadIdx.x;
    int n = row >> 4, o = row & 15;
    u64* bkey = z ? basekeyP : basekeyR;
    u32* lp = z ? plistP2 : plistP;
    u64* le = z ? plistE2 : plistE;
    u32* lc = z ? pcnt2 : pcnt;
    const u64* src = selk + ((size_t)z * ROWS + row) * 16;

    __shared__ int sh_num;
    if (tid == 0) {
        float s = 0.0f; int pc = 0;
        #pragma unroll
        for (int j = 0; j < 15; j++) {
            float v = keyval(src[j]);
            s += v;
            if (v > 0.0f) pc++;
        }
        int np = (int)s; if (np < 1) np = 1;
        if (pc == 0) {
            u64 bk = ((u64)__float_as_uint(3.0f) << 32) | (u32)(~(u32)o);
            atomicMax(&bkey[(size_t)n * P + 0], bk);
            u32 idx = atomicAdd(&lc[n], 1u);
            lp[n * 256 + idx] = 0u;
            le[n * 256 + idx] = bk;
            sh_num = 0;
        } else {
            sh_num = np;
        }
    }
    __syncthreads();
    if (tid < 15 && tid < sh_num) {
        u64 kx = src[tid];
        float v = keyval(kx);
        if (v > 0.0f) {
            u32 pidx = ~(u32)(kx & 0xFFFFFFFFULL);
            u64 bk = ((u64)__float_as_uint(v + 3.0f) << 32) | (u32)(~(u32)o);
            atomicMax(&bkey[(size_t)n * P + pidx], bk);
            u32 idx = atomicAdd(&lc[n], 1u);
            lp[n * 256 + idx] = pidx;
            le[n * 256 + idx] = bk;
        }
    }
}

// ---------- K4: fused tail — gfocal corrections + posCount + localization loss ------
__global__ __launch_bounds__(256) void k_tail(
        const float* __restrict__ conf, const float* __restrict__ loc,
        const float* __restrict__ priors, const float* __restrict__ truths,
        const int* __restrict__ labels,
        const u64* __restrict__ bkeyR, const u64* __restrict__ bkeyP,
        const u32* __restrict__ plistP, const u64* __restrict__ plistE,
        const u32* __restrict__ pcnt,
        const u32* __restrict__ plistP2, const u64* __restrict__ plistE2,
        const u32* __restrict__ pcnt2,
        double* __restrict__ partCC, u32* __restrict__ posCnt,
        double* __restrict__ partL, double* __restrict__ partR, int P) {
    int n = blockIdx.x, tid = threadIdx.x;
    __shared__ int lab[16];
    __shared__ float strt[64];
    if (tid < 16) lab[tid] = labels[n * 16 + tid];
    if (tid < 64) strt[tid] = truths[n * 64 + tid];
    __syncthreads();

    int cnt = (int)pcnt[n];
    float dsum = 0.0f;
    int mypos = 0;
    for (int t = tid; t < cnt; t += 256) {
        u32 p = plistP[n * 256 + t];
        u64 bk = plistE[n * 256 + t];
        u64 kx = bkeyR[(size_t)n * P + p];
        if (kx == bk) {
            float v3 = keyval(kx);
            float vt = v3 - 3.0f;
            if (vt > 0.0f) {
                mypos++;
                int o = (int)(~(u32)(kx & 0xFFFFFFFFULL)) & 15;
                int tcls = lab[o];
                float lg = conf[((size_t)n * P + p) * 80 + tcls];
                float e  = fexp2(-fabsf(lg) * LOG2E);
                float ln1pe = flog2(1.0f + e) * LN2;
                float rc = frcp(1.0f + e);
                float sg = (lg >= 0.0f) ? rc : e * rc;
                float bce0 = fmaxf(lg, 0.0f) + ln1pe;
                float bce1 = fmaxf(lg, 0.0f) - lg * vt + ln1pe;
                float d1 = sg - vt;
                dsum += d1 * d1 * bce1 - sg * sg * bce0;
            }
        }
    }

    int cnt2 = (int)pcnt2[n];
    float rsum = 0.0f, csum = 0.0f;
    for (int t = tid; t < cnt2; t += 256) {
        u32 p = plistP2[n * 256 + t];
        u64 bk = plistE2[n * 256 + t];
        u64 kx = bkeyP[(size_t)n * P + p];
        if (kx == bk) {
            float pt = keyval(kx);
            float r = pt - 3.0f;
            if (r > 0.0f) {
                int best = (int)(~(u32)(kx & 0xFFFFFFFFULL)) & 15;
                const float Bc   = (float)19.085536923187668;
                const float beta = 0.11f;
                float4 pr = *(const float4*)(priors + (size_t)p * 4);
                float tx1 = strt[best * 4],     ty1 = strt[best * 4 + 1];
                float tx2 = strt[best * 4 + 2], ty2 = strt[best * 4 + 3];
                float gcx = ((tx1 + tx2) * 0.5f - pr.x) / (0.1f * pr.z);
                float gcy = ((ty1 + ty2) * 0.5f - pr.y) / (0.1f * pr.w);
                float gw  = flog2((tx2 - tx1) / pr.z) * LN2 / 0.2f;
                float gh  = flog2((ty2 - ty1) / pr.w) * LN2 / 0.2f;
                float4 l  = *(const float4*)(loc + ((size_t)n * P + p) * 4);
                float tgt[4] = {gcx, gcy, gw, gh};
                float lvv[4] = {l.x, l.y, l.z, l.w};
                float s = 0.0f;
                #pragma unroll
                for (int j = 0; j < 4; j++) {
                    float diff = fabsf(lvv[j] - tgt[j]);
                    float bl;
                    if (diff < beta) {
                        bl = 0.5f / Bc * (Bc * diff + 1.0f) *
                             (flog2(1.0f + Bc * diff / beta) * LN2) - 0.5f * diff;
                    } else {
                        bl = 1.5f * diff + 1.5f / Bc - 0.5f * beta;
                    }
                    s += bl;
                }
                rsum += r;
                csum += r * s;
            }
        }
    }

    double dd = (double)dsum, dl = (double)csum, dr = (double)rsum;
    long long pp = mypos;
    #pragma unroll
    for (int s = 32; s > 0; s >>= 1) {
        dd += __shfl_down(dd, s, 64);
        dl += __shfl_down(dl, s, 64);
        dr += __shfl_down(dr, s, 64);
        pp += __shfl_down(pp, s, 64);
    }
    __shared__ double wd[4], wl[4], wr[4];
    __shared__ long long wp[4];
    int wv = tid >> 6;
    if ((tid & 63) == 0) { wd[wv] = dd; wl[wv] = dl; wr[wv] = dr; wp[wv] = pp; }
    __syncthreads();
    if (tid == 0) {
        partCC[n] = wd[0] + wd[1] + wd[2] + wd[3];
        partL[n]  = wl[0] + wl[1] + wl[2] + wl[3];
        partR[n]  = wr[0] + wr[1] + wr[2] + wr[3];
        posCnt[n] = (u32)(wp[0] + wp[1] + wp[2] + wp[3]);
    }
}

// ---------- K5: final reduction ----------
__global__ __launch_bounds__(256) void k_fin(
        const double* __restrict__ partC, int nC, const double* __restrict__ partCC,
        const double* __restrict__ partL, const double* __restrict__ partR,
        const u32* __restrict__ posCnt, int N, float* __restrict__ out) {
    int tid = threadIdx.x;
    double sC = 0, sL = 0, sR = 0;
    long long pos = 0;
    for (int i = tid; i < nC; i += 256) sC += partC[i];
    for (int i = tid; i < N; i += 256) {
        sC += partCC[i]; sL += partL[i]; sR += partR[i];
        pos += (long long)posCnt[i];
    }
    #pragma unroll
    for (int s = 32; s > 0; s >>= 1) {
        sC += __shfl_down(sC, s, 64);
        sL += __shfl_down(sL, s, 64);
        sR += __shfl_down(sR, s, 64);
        pos += __shfl_down(pos, s, 64);
    }
    __shared__ double aC[4], aL[4], aR[4];
    __shared__ long long aP[4];
    int wv = tid >> 6;
    if ((tid & 63) == 0) { aC[wv] = sC; aL[wv] = sL; aR[wv] = sR; aP[wv] = pos; }
    __syncthreads();
    if (tid == 0) {
        double tC = aC[0] + aC[1] + aC[2] + aC[3];
        double tL = aL[0] + aL[1] + aL[2] + aL[3];
        double tR = aR[0] + aR[1] + aR[2] + aR[3];
        long long tP = aP[0] + aP[1] + aP[2] + aP[3];
        double npos = tP > 0 ? (double)tP : 1.0;
        out[0] = (float)(tL / (4.0 * tR));
        out[1] = (float)(tC / npos);
    }
}

extern "C" void kernel_launch(void* const* d_in, const int* in_sizes, int n_in,
                              void* d_out, int out_size, void* d_ws, size_t ws_size,
                              hipStream_t stream) {
    const float* loc    = (const float*)d_in[0];
    const float* conf   = (const float*)d_in[1];
    const float* priors = (const float*)d_in[2];
    const float* truths = (const float*)d_in[3];
    const int*   labels = (const int*)d_in[4];

    int P = in_sizes[2] / 4;                 // 18000
    int N = in_sizes[0] / (P * 4);           // 32
    int NBLK = (P + 63) / 64;                // 282
    int ROWS = N * 16;                       // 512
    int nC = NBLK * N;                       // 9024
    // C == 80, O == 16, P even assumed by kernel tiling

    char* cur = (char*)d_ws;
    auto alloc = [&](size_t bytes) { char* r = cur; cur += (bytes + 255) & ~(size_t)255; return r; };
    u32* pcnt      = (u32*)alloc((size_t)N * 4);
    u32* pcnt2     = (u32*)alloc((size_t)N * 4);
    u32* posCnt    = (u32*)alloc((size_t)N * 4);
    double* partCC = (double*)alloc((size_t)N * 8);
    u32* plistP    = (u32*)alloc((size_t)N * 256 * 4);
    u64* plistE    = (u64*)alloc((size_t)N * 256 * 8);
    u32* plistP2   = (u32*)alloc((size_t)N * 256 * 4);
    u64* plistE2   = (u64*)alloc((size_t)N * 256 * 8);
    double* partC  = (double*)alloc((size_t)nC * 8);
    double* partL  = (double*)alloc((size_t)N * 8);
    double* partR  = (double*)alloc((size_t)N * 8);
    u64* selk      = (u64*)alloc((size_t)2 * ROWS * 16 * 8);
    u64* basekeyR  = (u64*)alloc((size_t)N * P * 8);
    u64* basekeyP  = (u64*)alloc((size_t)N * P * 8);
    float* out = (float*)d_out;

    dim3 blk(256);
    dim3 gridB(NBLK, N);
    dim3 gridS(ROWS, 2);

    k_main<<<gridB, blk, 0, stream>>>(loc, conf, priors, truths, labels,
                                      basekeyR, basekeyP, partC, pcnt, pcnt2, P);
    k_sel<<<gridS, blk, 0, stream>>>(basekeyR, basekeyP, selk, P, ROWS);
    k_boost<<<gridS, 64, 0, stream>>>(selk, basekeyR, basekeyP,
                                      plistP, plistE, pcnt,
                                      plistP2, plistE2, pcnt2, P, ROWS);
    k_tail<<<N, blk, 0, stream>>>(conf, loc, priors, truths, labels,
                                  basekeyR, basekeyP,
                                  plistP, plistE, pcnt,
                                  plistP2, plistE2, pcnt2,
                                  partCC, posCnt, partL, partR, P);
    k_fin<<<1, blk, 0, stream>>>(partC, nC, partCC, partL, partR, posCnt, N, out);
}